// Round 11
// baseline (623.142 us; speedup 1.0000x reference)
//
#include <hip/hip_runtime.h>

// 2-layer GCN via bucketed counting sort -> EXACT dst-sorted CSR -> register-
// accumulated node-parallel aggregation.
// R11: agg passes were pinned at ~133us across occupancy 22->73% and 7x fetch
// reduction (R5-R10) -> the invariant is the per-edge LDS fp32 atomicAdd
// structure. This version eliminates LDS atomics from aggregation: sort_nodes
// upgrades the bucket sort to an exact CSR (LDS hist + block scan + exact
// placement), then agg1/agg2 are thread-per-node register loops over
// contiguous segments with fused epilogues (no partials, no split).
// Edge record u32: rec = (src<<10) | (dst&1023)  (src < 2^22).
//
// Pipeline:
//   A  bucket_count : per-block LDS hist (4-way sub-hist) -> histM[bk][blkA]
//   B1 colscan      : exclusive scan of histM rows + totals
//   B2 bucketscan   : exclusive scan of totals -> bucketPtr
//   C  bucket_scatter: place recs via bucketPtr + colPrefix + LDS cursor
//   D  sort_nodes   : per bucket: LDS hist -> scan -> rowptr/dinv/th4(fp16);
//                     re-read records, exact placement -> srcfinal (full CSR)
//   E  agg1_fused   : per node: register-sum th4[src] over contiguous segment;
//                     + fp32 self; W1+ReLU+W2 -> z (float2 table, 4 MB)
//   F  agg2_fused   : per node: register-sum z[src]; + self -> out

#define SHIFT 10
#define BSZ   1024             // nodes per bucket
#define CH    32768            // edges per block in passes A/C
#define AC_THREADS 512
#define NBK_MAX 512
#define ST_THREADS 512         // sort_nodes block size

union F2U { float2 f2; unsigned long long u; };
union H4 { uint2 u; _Float16 h[4]; };

__device__ __forceinline__ int ntload_i(const int* p) { return __builtin_nontemporal_load(p); }
__device__ __forceinline__ unsigned int ntload_u(const unsigned int* p) { return __builtin_nontemporal_load(p); }

__global__ void bucket_count_kernel(const int* __restrict__ dst, int* __restrict__ histM,
                                    int E, int NBA, int NBK) {
    __shared__ int lhist[4 * NBK_MAX];
    int t = threadIdx.x;
    for (int b = t; b < 4 * NBK; b += AC_THREADS) lhist[b] = 0;
    __syncthreads();
    int sub = t & 3;
    int base = blockIdx.x * CH;
#pragma unroll 8
    for (int k = 0; k < CH / AC_THREADS; ++k) {
        int e = base + t + k * AC_THREADS;
        if (e < E) atomicAdd(&lhist[((ntload_i(&dst[e]) >> SHIFT) << 2) | sub], 1);
    }
    __syncthreads();
    for (int b = t; b < NBK; b += AC_THREADS)
        histM[(size_t)b * NBA + blockIdx.x] =
            lhist[4 * b] + lhist[4 * b + 1] + lhist[4 * b + 2] + lhist[4 * b + 3];
}

// Exclusive scan of one bucket's row histM[bk][0..NBA-1] in place; totals[bk]=sum.
__global__ void colscan_kernel(int* __restrict__ histM, int* __restrict__ totals,
                               int NBA) {
    __shared__ int sdata[256];
    int t = threadIdx.x;
    size_t base = (size_t)blockIdx.x * NBA;
    int v[4];
#pragma unroll
    for (int k = 0; k < 4; ++k) { int i = t * 4 + k; v[k] = (i < NBA) ? histM[base + i] : 0; }
    int s = v[0] + v[1] + v[2] + v[3];
    sdata[t] = s;
    __syncthreads();
    for (int off = 1; off < 256; off <<= 1) {
        int xv = (t >= off) ? sdata[t - off] : 0;
        __syncthreads();
        sdata[t] += xv;
        __syncthreads();
    }
    if (t == 255) totals[blockIdx.x] = sdata[255];
    int run = sdata[t] - s;
#pragma unroll
    for (int k = 0; k < 4; ++k) { int i = t * 4 + k; if (i < NBA) histM[base + i] = run; run += v[k]; }
}

// Exclusive scan of totals[NBK] -> bucketPtr; bucketPtr[NBK]=E. (NBK <= 1024)
__global__ void bucketscan_kernel(const int* __restrict__ totals, int* __restrict__ bucketPtr,
                                  int NBK, int E) {
    __shared__ int sdata[256];
    int t = threadIdx.x;
    int v[4];
#pragma unroll
    for (int k = 0; k < 4; ++k) { int i = t * 4 + k; v[k] = (i < NBK) ? totals[i] : 0; }
    int s = v[0] + v[1] + v[2] + v[3];
    sdata[t] = s;
    __syncthreads();
    for (int off = 1; off < 256; off <<= 1) {
        int xv = (t >= off) ? sdata[t - off] : 0;
        __syncthreads();
        sdata[t] += xv;
        __syncthreads();
    }
    int run = sdata[t] - s;
#pragma unroll
    for (int k = 0; k < 4; ++k) { int i = t * 4 + k; if (i < NBK) bucketPtr[i] = run; run += v[k]; }
    if (t == 255) bucketPtr[NBK] = E;
}

__global__ void bucket_scatter_kernel(const int* __restrict__ ei, const int* __restrict__ histM,
                                      const int* __restrict__ bucketPtr,
                                      unsigned int* __restrict__ sorted,
                                      int E, int NBA, int NBK) {
    __shared__ int cur[NBK_MAX];
    int t = threadIdx.x;
    for (int b = t; b < NBK; b += AC_THREADS)
        cur[b] = bucketPtr[b] + histM[(size_t)b * NBA + blockIdx.x];
    __syncthreads();
    int base = blockIdx.x * CH;
#pragma unroll 8
    for (int k = 0; k < CH / AC_THREADS; ++k) {
        int e = base + t + k * AC_THREADS;
        if (e < E) {
            int s = ntload_i(&ei[e]);
            int d = ntload_i(&ei[E + e]);
            int pos = atomicAdd(&cur[d >> SHIFT], 1);
            sorted[pos] = ((unsigned int)s << SHIFT) | (unsigned int)(d & (BSZ - 1));
        }
    }
}

// D: per bucket -- LDS hist of local dst, block scan -> rowptr/dinv/th4,
// then exact placement of src into srcfinal (full dst-sorted CSR).
__global__ void sort_nodes_kernel(const unsigned int* __restrict__ sorted,
                                  const int* __restrict__ bucketPtr,
                                  const float* __restrict__ x,
                                  int* __restrict__ rowptr,
                                  float* __restrict__ dinv,
                                  uint2* __restrict__ th4,
                                  int* __restrict__ srcfinal,
                                  int N, int E) {
    __shared__ int lh[BSZ];            // histogram (degree)
    __shared__ int lpre[BSZ];          // exclusive prefix -> placement cursor
    __shared__ int spair[ST_THREADS];  // scan temp
    int t = threadIdx.x;
    int bk = blockIdx.x;
    lh[t] = 0; lh[t + ST_THREADS] = 0;
    __syncthreads();
    int beg = bucketPtr[bk], end = bucketPtr[bk + 1];
    for (int j = beg + t; j < end; j += ST_THREADS)
        atomicAdd(&lh[ntload_u(&sorted[j]) & (BSZ - 1)], 1);
    __syncthreads();
    // exclusive scan over 1024 entries (2 per thread)
    int v0 = lh[2 * t], v1 = lh[2 * t + 1];
    int ps = v0 + v1;
    spair[t] = ps;
    __syncthreads();
    for (int off = 1; off < ST_THREADS; off <<= 1) {
        int xv = (t >= off) ? spair[t - off] : 0;
        __syncthreads();
        spair[t] += xv;
        __syncthreads();
    }
    int pairpre = spair[t] - ps;
    lpre[2 * t] = pairpre;
    lpre[2 * t + 1] = pairpre + v0;
    __syncthreads();
    // node outputs: rowptr, dinv, fp16 gather table
    for (int l = t; l < BSZ; l += ST_THREADS) {
        int i = (bk << SHIFT) + l;
        if (i < N) {
            rowptr[i] = beg + lpre[l];
            float di = rsqrtf((float)(lh[l] + 1));
            dinv[i] = di;
            float x0 = x[3 * i], x1 = x[3 * i + 1], x2 = x[3 * i + 2];
            H4 c;
            c.h[0] = (_Float16)(x0 * di);
            c.h[1] = (_Float16)(x1 * di);
            c.h[2] = (_Float16)(x2 * di);
            c.h[3] = (_Float16)0.f;
            th4[i] = c.u;
        }
    }
    if (bk == 0 && t == 0) rowptr[N] = E;
    __syncthreads();
    // exact placement; lpre doubles as per-node cursor
    for (int j = beg + t; j < end; j += ST_THREADS) {
        unsigned int rec = ntload_u(&sorted[j]);
        int ld = rec & (BSZ - 1);
        int pos = beg + atomicAdd(&lpre[ld], 1);
        srcfinal[pos] = (int)(rec >> SHIFT);
    }
}

// E: per-node register-accumulated aggregation over contiguous segment;
// fused self + W1 + ReLU + W2 -> z.
__global__ void agg1_fused_kernel(const int* __restrict__ rowptr,
                                  const int* __restrict__ srcfinal,
                                  const uint2* __restrict__ th4,
                                  const float* __restrict__ x,
                                  const float* __restrict__ dinv,
                                  const float* __restrict__ W1, const float* __restrict__ b1,
                                  const float* __restrict__ W2,
                                  float2* __restrict__ z, int N) {
    int i = blockIdx.x * blockDim.x + threadIdx.x;
    if (i >= N) return;
    int beg = rowptr[i], end = rowptr[i + 1];
    float a0 = 0.f, a1 = 0.f, a2 = 0.f;
    for (int j = beg; j < end; ++j) {
        int s = ntload_i(&srcfinal[j]);
        H4 c; c.u = th4[s];           // 8B gather, 4 MB table resident per XCD
        a0 += (float)c.h[0];
        a1 += (float)c.h[1];
        a2 += (float)c.h[2];
    }
    float di = dinv[i];
    float x0 = x[3 * i], x1 = x[3 * i + 1], x2 = x[3 * i + 2];
    float s0 = (a0 + x0 * di) * di;
    float s1 = (a1 + x1 * di) * di;
    float s2 = (a2 + x2 * di) * di;
    float m0 = 0.f, m1 = 0.f;
#pragma unroll
    for (int k = 0; k < 8; ++k) {
        float h = fmaxf(s0 * W1[k] + s1 * W1[8 + k] + s2 * W1[16 + k] + b1[k], 0.0f);
        m0 += h * W2[2 * k];
        m1 += h * W2[2 * k + 1];
    }
    z[i] = make_float2(m0 * di, m1 * di);
}

// F: per-node register-accumulated layer-2 aggregation; fused self -> out.
__global__ void agg2_fused_kernel(const int* __restrict__ rowptr,
                                  const int* __restrict__ srcfinal,
                                  const float2* __restrict__ z,
                                  const float* __restrict__ dinv,
                                  const float* __restrict__ b2,
                                  float* __restrict__ out, int N) {
    int i = blockIdx.x * blockDim.x + threadIdx.x;
    if (i >= N) return;
    int beg = rowptr[i], end = rowptr[i + 1];
    float a0 = 0.f, a1 = 0.f;
    for (int j = beg; j < end; ++j) {
        int s = ntload_i(&srcfinal[j]);
        float2 zv = z[s];             // 8B gather, 4 MB table resident per XCD
        a0 += zv.x;
        a1 += zv.y;
    }
    float di = dinv[i];
    float2 zs = z[i];
    out[(size_t)i * 2]     = di * (a0 + zs.x) + b2[0];
    out[(size_t)i * 2 + 1] = di * (a1 + zs.y) + b2[1];
}

extern "C" void kernel_launch(void* const* d_in, const int* in_sizes, int n_in,
                              void* d_out, int out_size, void* d_ws, size_t ws_size,
                              hipStream_t stream) {
    const float* x  = (const float*)d_in[0];
    const int*   ei = (const int*)d_in[1];   // [2, E] flat: src row, dst row
    const float* W1 = (const float*)d_in[2];
    const float* b1 = (const float*)d_in[3];
    const float* W2 = (const float*)d_in[4];
    const float* b2 = (const float*)d_in[5];
    float* out = (float*)d_out;

    const int N = in_sizes[0] / 3;
    const int E = in_sizes[1] / 2;
    const int NBK = (N + BSZ - 1) / BSZ;       // 489 buckets
    const int NBA = (E + CH - 1) / CH;         // 245 blocks in A/C

    // Workspace (~77 MB): histM, totals, bucketPtr, rowptr[N+1], dinv[N],
    // z[2N], th4[2N], sorted[E], srcfinal[E]. Every byte written before read.
    char* ws = (char*)d_ws;
    size_t off = 0;
    auto alloc = [&](size_t bytes) { char* p = ws + off; off = (off + bytes + 15) & ~(size_t)15; return p; };
    int* histM           = (int*)alloc((size_t)NBK * NBA * 4);
    int* totals          = (int*)alloc((size_t)NBK * 4);
    int* bucketPtr       = (int*)alloc(((size_t)NBK + 1) * 4);
    int* rowptr          = (int*)alloc(((size_t)N + 1) * 4);
    float* dinv          = (float*)alloc((size_t)N * 4);
    float2* z            = (float2*)alloc((size_t)N * 8);
    uint2* th4           = (uint2*)alloc((size_t)N * 8);
    unsigned int* sorted = (unsigned int*)alloc((size_t)E * 4);
    int* srcfinal        = (int*)alloc((size_t)E * 4);
    (void)ws_size;

    const int nb = (N + 255) / 256;

    bucket_count_kernel<<<NBA, AC_THREADS, 0, stream>>>(ei + E, histM, E, NBA, NBK);
    colscan_kernel<<<NBK, 256, 0, stream>>>(histM, totals, NBA);
    bucketscan_kernel<<<1, 256, 0, stream>>>(totals, bucketPtr, NBK, E);
    bucket_scatter_kernel<<<NBA, AC_THREADS, 0, stream>>>(ei, histM, bucketPtr, sorted, E, NBA, NBK);
    sort_nodes_kernel<<<NBK, ST_THREADS, 0, stream>>>(sorted, bucketPtr, x, rowptr, dinv, th4, srcfinal, N, E);
    agg1_fused_kernel<<<nb, 256, 0, stream>>>(rowptr, srcfinal, th4, x, dinv, W1, b1, W2, z, N);
    agg2_fused_kernel<<<nb, 256, 0, stream>>>(rowptr, srcfinal, z, dinv, b2, out, N);
}

// Round 12
// 458.240 us; speedup vs baseline: 1.3599x; 1.3599x over previous
//
#include <hip/hip_runtime.h>

// 2-layer GCN via bucketed counting sort + split-K LDS aggregation.
// R12 = R9 structure (best: 440us) + LDS-staged scatter flush.
// R9 recap: SHIFT=11 (BSZ=2048, NBK=245), fp16 4MB gather table (L2-resident),
// split-K (SPLIT=4) LDS-atomic aggregation with float4/float2 partials.
// R11 lesson: per-node register loops are WORSE than LDS-atomic split-K (agg
// wall is per-XCD L2 request rate ~4/cyc, not LDS atomics); exact-CSR
// placement writes 253MB (partial-line evictions). -> reverted.
// R12 change: bucket_scatter stages each 8192-edge round in LDS (hist -> scan
// -> ordered stage -> cooperative flush): consecutive lanes write consecutive
// global addresses per bucket (~130B runs) so L2 lines fill immediately.
// R9 scatter trickled 4B stores across block lifetime -> 183MB WRITE_SIZE.
// Edge record u32: rec = (src<<11) | (dst&2047)  (src < 2^19).

#define SHIFT 11
#define BSZ   2048             // nodes per bucket
#define CH    32768            // edges per block in passes A/C
#define RS    8192             // staging round size in scatter
#define AC_THREADS 512
#define NBK_MAX 256
#define AGG_THREADS 512
#define SPLIT 4                // sub-blocks per bucket in D1/E1/F1

typedef float vfloat4 __attribute__((ext_vector_type(4)));

union F2U { float2 f2; unsigned long long u; };
union H4 { uint2 u; _Float16 h[4]; };

__device__ __forceinline__ int ntload_i(const int* p) { return __builtin_nontemporal_load(p); }
__device__ __forceinline__ unsigned int ntload_u(const unsigned int* p) { return __builtin_nontemporal_load(p); }
__device__ __forceinline__ float2 ntload_f2(const float2* p) {
    F2U c; c.u = __builtin_nontemporal_load((const unsigned long long*)p); return c.f2;
}
__device__ __forceinline__ void ntstore_f2(float2 v, float2* p) {
    F2U c; c.f2 = v; __builtin_nontemporal_store(c.u, (unsigned long long*)p);
}
__device__ __forceinline__ void ntstore_f4(float4 v, float4* p) {
    vfloat4 nv = {v.x, v.y, v.z, v.w};
    __builtin_nontemporal_store(nv, (vfloat4*)p);
}
__device__ __forceinline__ float4 ntload_f4(const float4* p) {
    vfloat4 nv = __builtin_nontemporal_load((const vfloat4*)p);
    return make_float4(nv.x, nv.y, nv.z, nv.w);
}

__global__ void bucket_count_kernel(const int* __restrict__ dst, int* __restrict__ histM,
                                    int E, int NBA, int NBK) {
    __shared__ int lhist[4 * NBK_MAX];
    int t = threadIdx.x;
    for (int b = t; b < 4 * NBK; b += AC_THREADS) lhist[b] = 0;
    __syncthreads();
    int sub = t & 3;
    int base = blockIdx.x * CH;
#pragma unroll 8
    for (int k = 0; k < CH / AC_THREADS; ++k) {
        int e = base + t + k * AC_THREADS;
        if (e < E) atomicAdd(&lhist[((ntload_i(&dst[e]) >> SHIFT) << 2) | sub], 1);
    }
    __syncthreads();
    for (int b = t; b < NBK; b += AC_THREADS)
        histM[(size_t)b * NBA + blockIdx.x] =
            lhist[4 * b] + lhist[4 * b + 1] + lhist[4 * b + 2] + lhist[4 * b + 3];
}

// Exclusive scan of one bucket's row histM[bk][0..NBA-1] in place; totals[bk]=sum.
__global__ void colscan_kernel(int* __restrict__ histM, int* __restrict__ totals,
                               int NBA) {
    __shared__ int sdata[256];
    int t = threadIdx.x;
    size_t base = (size_t)blockIdx.x * NBA;
    int v[4];
#pragma unroll
    for (int k = 0; k < 4; ++k) { int i = t * 4 + k; v[k] = (i < NBA) ? histM[base + i] : 0; }
    int s = v[0] + v[1] + v[2] + v[3];
    sdata[t] = s;
    __syncthreads();
    for (int off = 1; off < 256; off <<= 1) {
        int xv = (t >= off) ? sdata[t - off] : 0;
        __syncthreads();
        sdata[t] += xv;
        __syncthreads();
    }
    if (t == 255) totals[blockIdx.x] = sdata[255];
    int run = sdata[t] - s;
#pragma unroll
    for (int k = 0; k < 4; ++k) { int i = t * 4 + k; if (i < NBA) histM[base + i] = run; run += v[k]; }
}

// Exclusive scan of totals[NBK] -> bucketPtr; bucketPtr[NBK]=E.
__global__ void bucketscan_kernel(const int* __restrict__ totals, int* __restrict__ bucketPtr,
                                  int NBK, int E) {
    __shared__ int sdata[256];
    int t = threadIdx.x;
    int v[4];
#pragma unroll
    for (int k = 0; k < 4; ++k) { int i = t * 4 + k; v[k] = (i < NBK) ? totals[i] : 0; }
    int s = v[0] + v[1] + v[2] + v[3];
    sdata[t] = s;
    __syncthreads();
    for (int off = 1; off < 256; off <<= 1) {
        int xv = (t >= off) ? sdata[t - off] : 0;
        __syncthreads();
        sdata[t] += xv;
        __syncthreads();
    }
    int run = sdata[t] - s;
#pragma unroll
    for (int k = 0; k < 4; ++k) { int i = t * 4 + k; if (i < NBK) bucketPtr[i] = run; run += v[k]; }
    if (t == 255) bucketPtr[NBK] = E;
}

// C: LDS-staged scatter. Per 8192-edge round: LDS hist -> scan -> ordered LDS
// stage -> cooperative flush (consecutive lanes -> consecutive global addrs).
__global__ void bucket_scatter_kernel(const int* __restrict__ ei, const int* __restrict__ histM,
                                      const int* __restrict__ bucketPtr,
                                      unsigned int* __restrict__ sorted,
                                      int E, int NBA, int NBK) {
    __shared__ unsigned int stage[RS];      // 32 KB
    __shared__ int hist[NBK_MAX];
    __shared__ int loff[NBK_MAX + 1];
    __shared__ int gcur[NBK_MAX];
    __shared__ int sdata[256];
    int t = threadIdx.x;
    for (int b = t; b < NBK; b += AC_THREADS)
        gcur[b] = bucketPtr[b] + histM[(size_t)b * NBA + blockIdx.x];
    const int EPT = RS / AC_THREADS;        // 16 edges per thread per round
    for (int round = 0; round < CH / RS; ++round) {
        int base = blockIdx.x * CH + round * RS;
        for (int b = t; b < NBK; b += AC_THREADS) hist[b] = 0;
        __syncthreads();
        int bb[EPT]; unsigned int rr[EPT]; int rk[EPT];
#pragma unroll
        for (int k = 0; k < EPT; ++k) {
            int e = base + k * AC_THREADS + t;
            if (e < E) {
                int s = ntload_i(&ei[e]);
                int d = ntload_i(&ei[E + e]);
                bb[k] = d >> SHIFT;
                rr[k] = ((unsigned int)s << SHIFT) | (unsigned int)(d & (BSZ - 1));
                rk[k] = atomicAdd(&hist[bb[k]], 1);
            } else bb[k] = -1;
        }
        __syncthreads();
        // exclusive scan of hist[0..NBK) with threads 0..255 (all threads hit barriers)
        int v = 0;
        if (t < 256) { v = (t < NBK) ? hist[t] : 0; sdata[t] = v; }
        __syncthreads();
        for (int off = 1; off < 256; off <<= 1) {
            int xv = (t >= off && t < 256) ? sdata[t - off] : 0;
            __syncthreads();
            if (t < 256) sdata[t] += xv;
            __syncthreads();
        }
        if (t < 256) loff[t] = sdata[t] - v;
        if (t == 255) loff[NBK] = sdata[255];
        __syncthreads();
#pragma unroll
        for (int k = 0; k < EPT; ++k)
            if (bb[k] >= 0) stage[loff[bb[k]] + rk[k]] = rr[k];
        __syncthreads();
        int total = loff[NBK];
        for (int k = t; k < total; k += AC_THREADS) {
            int lo = 0, hi = NBK;                 // find b: loff[b] <= k < loff[b+1]
            while (hi - lo > 1) { int mid = (lo + hi) >> 1; if (loff[mid] <= k) lo = mid; else hi = mid; }
            sorted[gcur[lo] + (k - loff[lo])] = stage[k];
        }
        __syncthreads();
        for (int b = t; b < NBK; b += AC_THREADS) gcur[b] += hist[b];
        __syncthreads();
    }
}

// D1: split-K per-node degree histogram -> partialD[sp][node].
__global__ void deg_partial_kernel(const unsigned int* __restrict__ sorted,
                                   const int* __restrict__ bucketPtr,
                                   int* __restrict__ partialD, int N) {
    __shared__ int lhist[BSZ];
    int t = threadIdx.x;
    int bk = blockIdx.x >> 2, sp = blockIdx.x & 3;
    for (int l = t; l < BSZ; l += AGG_THREADS) lhist[l] = 0;
    __syncthreads();
    int beg = bucketPtr[bk], end = bucketPtr[bk + 1], len = end - beg;
    int s0 = beg + (int)(((long long)len * sp) >> 2);
    int s1 = beg + (int)(((long long)len * (sp + 1)) >> 2);
    for (int j = s0 + t; j < s1; j += AGG_THREADS)
        atomicAdd(&lhist[ntload_u(&sorted[j]) & (BSZ - 1)], 1);
    __syncthreads();
    size_t base = (size_t)sp * N;
    for (int l = t; l < BSZ; l += AGG_THREADS) {
        int i = (bk << SHIFT) + l;
        if (i < N) __builtin_nontemporal_store(lhist[l], &partialD[base + i]);
    }
}

// D2: deg = sum of partials; dinv = rsqrt(deg+1); th4 = fp16{x*dinv, pad}.
__global__ void dinv_xd_kernel(const int* __restrict__ partialD, const float* __restrict__ x,
                               float* __restrict__ dinv, uint2* __restrict__ th4, int N) {
    int i = blockIdx.x * blockDim.x + threadIdx.x;
    if (i >= N) return;
    int deg = ntload_i(&partialD[i]) + ntload_i(&partialD[(size_t)N + i]) +
              ntload_i(&partialD[2 * (size_t)N + i]) + ntload_i(&partialD[3 * (size_t)N + i]);
    float di = rsqrtf((float)(deg + 1));
    dinv[i] = di;
    float x0 = x[3 * i], x1 = x[3 * i + 1], x2 = x[3 * i + 2];
    H4 c;
    c.h[0] = (_Float16)(x0 * di);
    c.h[1] = (_Float16)(x1 * di);
    c.h[2] = (_Float16)(x2 * di);
    c.h[3] = (_Float16)0.f;
    th4[i] = c.u;
}

// E1: split-K LDS fp32 accumulation of fp16 th4[src] (4 MB resident) -> partial1.
__global__ void agg1_partial_kernel(const unsigned int* __restrict__ sorted,
                                    const int* __restrict__ bucketPtr,
                                    const uint2* __restrict__ th4,
                                    float4* __restrict__ partial1, int N) {
    __shared__ float a0[BSZ], a1[BSZ], a2[BSZ];
    int t = threadIdx.x;
    int bk = blockIdx.x >> 2, sp = blockIdx.x & 3;
    for (int l = t; l < BSZ; l += AGG_THREADS) { a0[l] = 0.f; a1[l] = 0.f; a2[l] = 0.f; }
    __syncthreads();
    int beg = bucketPtr[bk], end = bucketPtr[bk + 1], len = end - beg;
    int s0 = beg + (int)(((long long)len * sp) >> 2);
    int s1 = beg + (int)(((long long)len * (sp + 1)) >> 2);
    for (int j = s0 + t; j < s1; j += AGG_THREADS) {
        unsigned int rec = ntload_u(&sorted[j]);
        int s = rec >> SHIFT;
        int ld = rec & (BSZ - 1);
        H4 c; c.u = th4[s];
        atomicAdd(&a0[ld], (float)c.h[0]);
        atomicAdd(&a1[ld], (float)c.h[1]);
        atomicAdd(&a2[ld], (float)c.h[2]);
    }
    __syncthreads();
    size_t base = (size_t)sp * N;
    for (int l = t; l < BSZ; l += AGG_THREADS) {
        int i = (bk << SHIFT) + l;
        if (i < N) ntstore_f4(make_float4(a0[l], a1[l], a2[l], 0.0f), &partial1[base + i]);
    }
}

// E2: sum partials + fp32 self; fused W1 + ReLU + W2 -> z (float2 table, 4 MB).
__global__ void z_epilogue_kernel(const float4* __restrict__ partial1,
                                  const float* __restrict__ x, const float* __restrict__ dinv,
                                  const float* __restrict__ W1, const float* __restrict__ b1,
                                  const float* __restrict__ W2, float2* __restrict__ z, int N) {
    int i = blockIdx.x * blockDim.x + threadIdx.x;
    if (i >= N) return;
    float4 p0 = ntload_f4(&partial1[i]);
    float4 p1 = ntload_f4(&partial1[(size_t)N + i]);
    float4 p2 = ntload_f4(&partial1[2 * (size_t)N + i]);
    float4 p3 = ntload_f4(&partial1[3 * (size_t)N + i]);
    float di = dinv[i];
    float x0 = x[3 * i], x1 = x[3 * i + 1], x2 = x[3 * i + 2];
    float s0 = (p0.x + p1.x + p2.x + p3.x + x0 * di) * di;
    float s1 = (p0.y + p1.y + p2.y + p3.y + x1 * di) * di;
    float s2 = (p0.z + p1.z + p2.z + p3.z + x2 * di) * di;
    float m0 = 0.f, m1 = 0.f;
#pragma unroll
    for (int k = 0; k < 8; ++k) {
        float h = fmaxf(s0 * W1[k] + s1 * W1[8 + k] + s2 * W1[16 + k] + b1[k], 0.0f);
        m0 += h * W2[2 * k];
        m1 += h * W2[2 * k + 1];
    }
    z[i] = make_float2(m0 * di, m1 * di);
}

// F1: split-K LDS accumulation of z[src] (4 MB resident) -> p2 (float2).
__global__ void agg2_partial_kernel(const unsigned int* __restrict__ sorted,
                                    const int* __restrict__ bucketPtr,
                                    const float2* __restrict__ z,
                                    float2* __restrict__ p2, int N) {
    __shared__ float a0[BSZ], a1[BSZ];
    int t = threadIdx.x;
    int bk = blockIdx.x >> 2, sp = blockIdx.x & 3;
    for (int l = t; l < BSZ; l += AGG_THREADS) { a0[l] = 0.f; a1[l] = 0.f; }
    __syncthreads();
    int beg = bucketPtr[bk], end = bucketPtr[bk + 1], len = end - beg;
    int s0 = beg + (int)(((long long)len * sp) >> 2);
    int s1 = beg + (int)(((long long)len * (sp + 1)) >> 2);
    for (int j = s0 + t; j < s1; j += AGG_THREADS) {
        unsigned int rec = ntload_u(&sorted[j]);
        int s = rec >> SHIFT;
        int ld = rec & (BSZ - 1);
        float2 zv = z[s];
        atomicAdd(&a0[ld], zv.x);
        atomicAdd(&a1[ld], zv.y);
    }
    __syncthreads();
    size_t base = (size_t)sp * N;
    for (int l = t; l < BSZ; l += AGG_THREADS) {
        int i = (bk << SHIFT) + l;
        if (i < N) ntstore_f2(make_float2(a0[l], a1[l]), &p2[base + i]);
    }
}

// F2: sum partials + self -> out.
__global__ void out_epilogue_kernel(const float2* __restrict__ p2,
                                    const float2* __restrict__ z, const float* __restrict__ dinv,
                                    const float* __restrict__ b2, float* __restrict__ out, int N) {
    int i = blockIdx.x * blockDim.x + threadIdx.x;
    if (i >= N) return;
    float2 q0 = ntload_f2(&p2[i]);
    float2 q1 = ntload_f2(&p2[(size_t)N + i]);
    float2 q2 = ntload_f2(&p2[2 * (size_t)N + i]);
    float2 q3 = ntload_f2(&p2[3 * (size_t)N + i]);
    const float2 zs = z[i];
    float di = dinv[i];
    out[(size_t)i * 2]     = di * (q0.x + q1.x + q2.x + q3.x + zs.x) + b2[0];
    out[(size_t)i * 2 + 1] = di * (q0.y + q1.y + q2.y + q3.y + zs.y) + b2[1];
}

extern "C" void kernel_launch(void* const* d_in, const int* in_sizes, int n_in,
                              void* d_out, int out_size, void* d_ws, size_t ws_size,
                              hipStream_t stream) {
    const float* x  = (const float*)d_in[0];
    const int*   ei = (const int*)d_in[1];   // [2, E] flat: src row, dst row
    const float* W1 = (const float*)d_in[2];
    const float* b1 = (const float*)d_in[3];
    const float* W2 = (const float*)d_in[4];
    const float* b2 = (const float*)d_in[5];
    float* out = (float*)d_out;

    const int N = in_sizes[0] / 3;
    const int E = in_sizes[1] / 2;
    const int NBK = (N + BSZ - 1) / BSZ;       // 245 buckets
    const int NBA = (E + CH - 1) / CH;         // 245 blocks in A/C

    // Workspace. `scratch` (32 MB) reused sequentially: partialD (D1->D2),
    // then partial1 (E1->E2), then p2 (F1->F2). All bytes written before read.
    char* ws = (char*)d_ws;
    size_t off = 0;
    auto alloc = [&](size_t bytes) { char* p = ws + off; off = (off + bytes + 15) & ~(size_t)15; return p; };
    int* histM           = (int*)alloc((size_t)NBK * NBA * 4);
    int* totals          = (int*)alloc((size_t)NBK * 4);
    int* bucketPtr       = (int*)alloc(((size_t)NBK + 1) * 4);
    char* scratch        = alloc((size_t)SPLIT * N * 16);
    float* dinv          = (float*)alloc((size_t)N * 4);
    float2* z            = (float2*)alloc((size_t)N * 8);
    uint2* th4           = (uint2*)alloc((size_t)N * 8);
    unsigned int* sorted = (unsigned int*)alloc((size_t)E * 4);
    (void)ws_size;

    int* partialD    = (int*)scratch;
    float4* partial1 = (float4*)scratch;     // SPLIT*N*16
    float2* p2       = (float2*)scratch;     // SPLIT*N*8

    const int nb = (N + 255) / 256;

    bucket_count_kernel<<<NBA, AC_THREADS, 0, stream>>>(ei + E, histM, E, NBA, NBK);
    colscan_kernel<<<NBK, 256, 0, stream>>>(histM, totals, NBA);
    bucketscan_kernel<<<1, 256, 0, stream>>>(totals, bucketPtr, NBK, E);
    bucket_scatter_kernel<<<NBA, AC_THREADS, 0, stream>>>(ei, histM, bucketPtr, sorted, E, NBA, NBK);
    deg_partial_kernel<<<NBK * SPLIT, AGG_THREADS, 0, stream>>>(sorted, bucketPtr, partialD, N);
    dinv_xd_kernel<<<nb, 256, 0, stream>>>(partialD, x, dinv, th4, N);
    agg1_partial_kernel<<<NBK * SPLIT, AGG_THREADS, 0, stream>>>(sorted, bucketPtr, th4, partial1, N);
    z_epilogue_kernel<<<nb, 256, 0, stream>>>(partial1, x, dinv, W1, b1, W2, z, N);
    agg2_partial_kernel<<<NBK * SPLIT, AGG_THREADS, 0, stream>>>(sorted, bucketPtr, z, p2, N);
    out_epilogue_kernel<<<nb, 256, 0, stream>>>(p2, z, dinv, b2, out, N);
}

// Round 13
// 439.871 us; speedup vs baseline: 1.4166x; 1.0418x over previous
//
#include <hip/hip_runtime.h>

// 2-layer GCN via bucketed counting sort + split-K LDS aggregation.
// R13 = R9 structure (best: 440us) with ONE change: LDS fp32 atomicAdd ->
// unsafeAtomicAdd (native ds_add_f32). Theory: HIP lowers fp32 atomicAdd to a
// CAS retry loop (safe-fp-atomics default); a 64-lane CAS storm on LDS
// explains agg1's invariant ~133us across occupancy 22->73%, table 16->4MB,
// fetch 279->40MB (R5-R12), and R1's 20G atomics/s global rate. Int atomics
// (deg/scatter/count) are native and never bottlenecked.
// Edge record u32: rec = (src<<11) | (dst&2047)  (src < 2^19).
//
// Pipeline (zero global atomics; LDS atomics only):
//   A  bucket_count   : per-block LDS hist (4-way sub-hist) -> histM[bk][blkA]
//   B1 colscan        : exclusive scan of histM rows + totals
//   B2 bucketscan     : exclusive scan of totals -> bucketPtr
//   C  bucket_scatter : place recs via bucketPtr + colPrefix + LDS cursor
//   D1 deg_partial    : split-K LDS hist -> partialD[sp][node]
//   D2 dinv_xd        : deg=sum partials; dinv=rsqrt(deg+1); th4=fp16(x*dinv)
//   E1 agg1_partial   : split-K LDS fp32 accum (ds_add_f32) of th4[src]
//                       (4MB L2-resident fp16 table) -> partial1 (float4)
//   E2 z_epilogue     : sum partials + fp32 self; W1+ReLU+W2 -> z (float2, 4MB)
//   F1 agg2_partial   : split-K LDS accum (ds_add_f32) of z[src] -> p2
//   F2 out_epilogue   : sum partials + self -> out

#define SHIFT 11
#define BSZ   2048             // nodes per bucket
#define CH    32768            // edges per block in passes A/C
#define AC_THREADS 512
#define NBK_MAX 256
#define AGG_THREADS 512
#define SPLIT 4                // sub-blocks per bucket in D1/E1/F1

typedef float vfloat4 __attribute__((ext_vector_type(4)));

union F2U { float2 f2; unsigned long long u; };
union H4 { uint2 u; _Float16 h[4]; };

__device__ __forceinline__ int ntload_i(const int* p) { return __builtin_nontemporal_load(p); }
__device__ __forceinline__ unsigned int ntload_u(const unsigned int* p) { return __builtin_nontemporal_load(p); }
__device__ __forceinline__ float2 ntload_f2(const float2* p) {
    F2U c; c.u = __builtin_nontemporal_load((const unsigned long long*)p); return c.f2;
}
__device__ __forceinline__ void ntstore_f2(float2 v, float2* p) {
    F2U c; c.f2 = v; __builtin_nontemporal_store(c.u, (unsigned long long*)p);
}
__device__ __forceinline__ void ntstore_f4(float4 v, float4* p) {
    vfloat4 nv = {v.x, v.y, v.z, v.w};
    __builtin_nontemporal_store(nv, (vfloat4*)p);
}
__device__ __forceinline__ float4 ntload_f4(const float4* p) {
    vfloat4 nv = __builtin_nontemporal_load((const vfloat4*)p);
    return make_float4(nv.x, nv.y, nv.z, nv.w);
}

__global__ void bucket_count_kernel(const int* __restrict__ dst, int* __restrict__ histM,
                                    int E, int NBA, int NBK) {
    __shared__ int lhist[4 * NBK_MAX];
    int t = threadIdx.x;
    for (int b = t; b < 4 * NBK; b += AC_THREADS) lhist[b] = 0;
    __syncthreads();
    int sub = t & 3;
    int base = blockIdx.x * CH;
#pragma unroll 8
    for (int k = 0; k < CH / AC_THREADS; ++k) {
        int e = base + t + k * AC_THREADS;
        if (e < E) atomicAdd(&lhist[((ntload_i(&dst[e]) >> SHIFT) << 2) | sub], 1);
    }
    __syncthreads();
    for (int b = t; b < NBK; b += AC_THREADS)
        histM[(size_t)b * NBA + blockIdx.x] =
            lhist[4 * b] + lhist[4 * b + 1] + lhist[4 * b + 2] + lhist[4 * b + 3];
}

// Exclusive scan of one bucket's row histM[bk][0..NBA-1] in place; totals[bk]=sum.
__global__ void colscan_kernel(int* __restrict__ histM, int* __restrict__ totals,
                               int NBA) {
    __shared__ int sdata[256];
    int t = threadIdx.x;
    size_t base = (size_t)blockIdx.x * NBA;
    int v[4];
#pragma unroll
    for (int k = 0; k < 4; ++k) { int i = t * 4 + k; v[k] = (i < NBA) ? histM[base + i] : 0; }
    int s = v[0] + v[1] + v[2] + v[3];
    sdata[t] = s;
    __syncthreads();
    for (int off = 1; off < 256; off <<= 1) {
        int xv = (t >= off) ? sdata[t - off] : 0;
        __syncthreads();
        sdata[t] += xv;
        __syncthreads();
    }
    if (t == 255) totals[blockIdx.x] = sdata[255];
    int run = sdata[t] - s;
#pragma unroll
    for (int k = 0; k < 4; ++k) { int i = t * 4 + k; if (i < NBA) histM[base + i] = run; run += v[k]; }
}

// Exclusive scan of totals[NBK] -> bucketPtr; bucketPtr[NBK]=E.
__global__ void bucketscan_kernel(const int* __restrict__ totals, int* __restrict__ bucketPtr,
                                  int NBK, int E) {
    __shared__ int sdata[256];
    int t = threadIdx.x;
    int v[4];
#pragma unroll
    for (int k = 0; k < 4; ++k) { int i = t * 4 + k; v[k] = (i < NBK) ? totals[i] : 0; }
    int s = v[0] + v[1] + v[2] + v[3];
    sdata[t] = s;
    __syncthreads();
    for (int off = 1; off < 256; off <<= 1) {
        int xv = (t >= off) ? sdata[t - off] : 0;
        __syncthreads();
        sdata[t] += xv;
        __syncthreads();
    }
    int run = sdata[t] - s;
#pragma unroll
    for (int k = 0; k < 4; ++k) { int i = t * 4 + k; if (i < NBK) bucketPtr[i] = run; run += v[k]; }
    if (t == 255) bucketPtr[NBK] = E;
}

__global__ void bucket_scatter_kernel(const int* __restrict__ ei, const int* __restrict__ histM,
                                      const int* __restrict__ bucketPtr,
                                      unsigned int* __restrict__ sorted,
                                      int E, int NBA, int NBK) {
    __shared__ int cur[NBK_MAX];
    int t = threadIdx.x;
    for (int b = t; b < NBK; b += AC_THREADS)
        cur[b] = bucketPtr[b] + histM[(size_t)b * NBA + blockIdx.x];
    __syncthreads();
    int base = blockIdx.x * CH;
#pragma unroll 8
    for (int k = 0; k < CH / AC_THREADS; ++k) {
        int e = base + t + k * AC_THREADS;
        if (e < E) {
            int s = ntload_i(&ei[e]);
            int d = ntload_i(&ei[E + e]);
            int pos = atomicAdd(&cur[d >> SHIFT], 1);
            sorted[pos] = ((unsigned int)s << SHIFT) | (unsigned int)(d & (BSZ - 1));
        }
    }
}

// D1: split-K per-node degree histogram -> partialD[sp][node].
__global__ void deg_partial_kernel(const unsigned int* __restrict__ sorted,
                                   const int* __restrict__ bucketPtr,
                                   int* __restrict__ partialD, int N) {
    __shared__ int lhist[BSZ];
    int t = threadIdx.x;
    int bk = blockIdx.x >> 2, sp = blockIdx.x & 3;
    for (int l = t; l < BSZ; l += AGG_THREADS) lhist[l] = 0;
    __syncthreads();
    int beg = bucketPtr[bk], end = bucketPtr[bk + 1], len = end - beg;
    int s0 = beg + (int)(((long long)len * sp) >> 2);
    int s1 = beg + (int)(((long long)len * (sp + 1)) >> 2);
    for (int j = s0 + t; j < s1; j += AGG_THREADS)
        atomicAdd(&lhist[ntload_u(&sorted[j]) & (BSZ - 1)], 1);
    __syncthreads();
    size_t base = (size_t)sp * N;
    for (int l = t; l < BSZ; l += AGG_THREADS) {
        int i = (bk << SHIFT) + l;
        if (i < N) __builtin_nontemporal_store(lhist[l], &partialD[base + i]);
    }
}

// D2: deg = sum of partials; dinv = rsqrt(deg+1); th4 = fp16{x*dinv, pad}.
__global__ void dinv_xd_kernel(const int* __restrict__ partialD, const float* __restrict__ x,
                               float* __restrict__ dinv, uint2* __restrict__ th4, int N) {
    int i = blockIdx.x * blockDim.x + threadIdx.x;
    if (i >= N) return;
    int deg = ntload_i(&partialD[i]) + ntload_i(&partialD[(size_t)N + i]) +
              ntload_i(&partialD[2 * (size_t)N + i]) + ntload_i(&partialD[3 * (size_t)N + i]);
    float di = rsqrtf((float)(deg + 1));
    dinv[i] = di;
    float x0 = x[3 * i], x1 = x[3 * i + 1], x2 = x[3 * i + 2];
    H4 c;
    c.h[0] = (_Float16)(x0 * di);
    c.h[1] = (_Float16)(x1 * di);
    c.h[2] = (_Float16)(x2 * di);
    c.h[3] = (_Float16)0.f;
    th4[i] = c.u;
}

// E1: split-K LDS fp32 accumulation (native ds_add_f32 via unsafeAtomicAdd)
// of fp16 th4[src] (4 MB resident) -> partial1.
__global__ void agg1_partial_kernel(const unsigned int* __restrict__ sorted,
                                    const int* __restrict__ bucketPtr,
                                    const uint2* __restrict__ th4,
                                    float4* __restrict__ partial1, int N) {
    __shared__ float a0[BSZ], a1[BSZ], a2[BSZ];
    int t = threadIdx.x;
    int bk = blockIdx.x >> 2, sp = blockIdx.x & 3;
    for (int l = t; l < BSZ; l += AGG_THREADS) { a0[l] = 0.f; a1[l] = 0.f; a2[l] = 0.f; }
    __syncthreads();
    int beg = bucketPtr[bk], end = bucketPtr[bk + 1], len = end - beg;
    int s0 = beg + (int)(((long long)len * sp) >> 2);
    int s1 = beg + (int)(((long long)len * (sp + 1)) >> 2);
    for (int j = s0 + t; j < s1; j += AGG_THREADS) {
        unsigned int rec = ntload_u(&sorted[j]);
        int s = rec >> SHIFT;
        int ld = rec & (BSZ - 1);
        H4 c; c.u = th4[s];
        unsafeAtomicAdd(&a0[ld], (float)c.h[0]);   // ds_add_f32, no CAS loop
        unsafeAtomicAdd(&a1[ld], (float)c.h[1]);
        unsafeAtomicAdd(&a2[ld], (float)c.h[2]);
    }
    __syncthreads();
    size_t base = (size_t)sp * N;
    for (int l = t; l < BSZ; l += AGG_THREADS) {
        int i = (bk << SHIFT) + l;
        if (i < N) ntstore_f4(make_float4(a0[l], a1[l], a2[l], 0.0f), &partial1[base + i]);
    }
}

// E2: sum partials + fp32 self; fused W1 + ReLU + W2 -> z (float2 table, 4 MB).
__global__ void z_epilogue_kernel(const float4* __restrict__ partial1,
                                  const float* __restrict__ x, const float* __restrict__ dinv,
                                  const float* __restrict__ W1, const float* __restrict__ b1,
                                  const float* __restrict__ W2, float2* __restrict__ z, int N) {
    int i = blockIdx.x * blockDim.x + threadIdx.x;
    if (i >= N) return;
    float4 p0 = ntload_f4(&partial1[i]);
    float4 p1 = ntload_f4(&partial1[(size_t)N + i]);
    float4 p2 = ntload_f4(&partial1[2 * (size_t)N + i]);
    float4 p3 = ntload_f4(&partial1[3 * (size_t)N + i]);
    float di = dinv[i];
    float x0 = x[3 * i], x1 = x[3 * i + 1], x2 = x[3 * i + 2];
    float s0 = (p0.x + p1.x + p2.x + p3.x + x0 * di) * di;
    float s1 = (p0.y + p1.y + p2.y + p3.y + x1 * di) * di;
    float s2 = (p0.z + p1.z + p2.z + p3.z + x2 * di) * di;
    float m0 = 0.f, m1 = 0.f;
#pragma unroll
    for (int k = 0; k < 8; ++k) {
        float h = fmaxf(s0 * W1[k] + s1 * W1[8 + k] + s2 * W1[16 + k] + b1[k], 0.0f);
        m0 += h * W2[2 * k];
        m1 += h * W2[2 * k + 1];
    }
    z[i] = make_float2(m0 * di, m1 * di);
}

// F1: split-K LDS accumulation (ds_add_f32) of z[src] (4 MB resident) -> p2.
__global__ void agg2_partial_kernel(const unsigned int* __restrict__ sorted,
                                    const int* __restrict__ bucketPtr,
                                    const float2* __restrict__ z,
                                    float2* __restrict__ p2, int N) {
    __shared__ float a0[BSZ], a1[BSZ];
    int t = threadIdx.x;
    int bk = blockIdx.x >> 2, sp = blockIdx.x & 3;
    for (int l = t; l < BSZ; l += AGG_THREADS) { a0[l] = 0.f; a1[l] = 0.f; }
    __syncthreads();
    int beg = bucketPtr[bk], end = bucketPtr[bk + 1], len = end - beg;
    int s0 = beg + (int)(((long long)len * sp) >> 2);
    int s1 = beg + (int)(((long long)len * (sp + 1)) >> 2);
    for (int j = s0 + t; j < s1; j += AGG_THREADS) {
        unsigned int rec = ntload_u(&sorted[j]);
        int s = rec >> SHIFT;
        int ld = rec & (BSZ - 1);
        float2 zv = z[s];
        unsafeAtomicAdd(&a0[ld], zv.x);            // ds_add_f32
        unsafeAtomicAdd(&a1[ld], zv.y);
    }
    __syncthreads();
    size_t base = (size_t)sp * N;
    for (int l = t; l < BSZ; l += AGG_THREADS) {
        int i = (bk << SHIFT) + l;
        if (i < N) ntstore_f2(make_float2(a0[l], a1[l]), &p2[base + i]);
    }
}

// F2: sum partials + self -> out.
__global__ void out_epilogue_kernel(const float2* __restrict__ p2,
                                    const float2* __restrict__ z, const float* __restrict__ dinv,
                                    const float* __restrict__ b2, float* __restrict__ out, int N) {
    int i = blockIdx.x * blockDim.x + threadIdx.x;
    if (i >= N) return;
    float2 q0 = ntload_f2(&p2[i]);
    float2 q1 = ntload_f2(&p2[(size_t)N + i]);
    float2 q2 = ntload_f2(&p2[2 * (size_t)N + i]);
    float2 q3 = ntload_f2(&p2[3 * (size_t)N + i]);
    const float2 zs = z[i];
    float di = dinv[i];
    out[(size_t)i * 2]     = di * (q0.x + q1.x + q2.x + q3.x + zs.x) + b2[0];
    out[(size_t)i * 2 + 1] = di * (q0.y + q1.y + q2.y + q3.y + zs.y) + b2[1];
}

extern "C" void kernel_launch(void* const* d_in, const int* in_sizes, int n_in,
                              void* d_out, int out_size, void* d_ws, size_t ws_size,
                              hipStream_t stream) {
    const float* x  = (const float*)d_in[0];
    const int*   ei = (const int*)d_in[1];   // [2, E] flat: src row, dst row
    const float* W1 = (const float*)d_in[2];
    const float* b1 = (const float*)d_in[3];
    const float* W2 = (const float*)d_in[4];
    const float* b2 = (const float*)d_in[5];
    float* out = (float*)d_out;

    const int N = in_sizes[0] / 3;
    const int E = in_sizes[1] / 2;
    const int NBK = (N + BSZ - 1) / BSZ;       // 245 buckets
    const int NBA = (E + CH - 1) / CH;         // 245 blocks in A/C

    // Workspace. `scratch` (32 MB) reused sequentially: partialD (D1->D2),
    // then partial1 (E1->E2), then p2 (F1->F2). All bytes written before read.
    char* ws = (char*)d_ws;
    size_t off = 0;
    auto alloc = [&](size_t bytes) { char* p = ws + off; off = (off + bytes + 15) & ~(size_t)15; return p; };
    int* histM           = (int*)alloc((size_t)NBK * NBA * 4);
    int* totals          = (int*)alloc((size_t)NBK * 4);
    int* bucketPtr       = (int*)alloc(((size_t)NBK + 1) * 4);
    char* scratch        = alloc((size_t)SPLIT * N * 16);
    float* dinv          = (float*)alloc((size_t)N * 4);
    float2* z            = (float2*)alloc((size_t)N * 8);
    uint2* th4           = (uint2*)alloc((size_t)N * 8);
    unsigned int* sorted = (unsigned int*)alloc((size_t)E * 4);
    (void)ws_size;

    int* partialD    = (int*)scratch;
    float4* partial1 = (float4*)scratch;     // SPLIT*N*16
    float2* p2       = (float2*)scratch;     // SPLIT*N*8

    const int nb = (N + 255) / 256;

    bucket_count_kernel<<<NBA, AC_THREADS, 0, stream>>>(ei + E, histM, E, NBA, NBK);
    colscan_kernel<<<NBK, 256, 0, stream>>>(histM, totals, NBA);
    bucketscan_kernel<<<1, 256, 0, stream>>>(totals, bucketPtr, NBK, E);
    bucket_scatter_kernel<<<NBA, AC_THREADS, 0, stream>>>(ei, histM, bucketPtr, sorted, E, NBA, NBK);
    deg_partial_kernel<<<NBK * SPLIT, AGG_THREADS, 0, stream>>>(sorted, bucketPtr, partialD, N);
    dinv_xd_kernel<<<nb, 256, 0, stream>>>(partialD, x, dinv, th4, N);
    agg1_partial_kernel<<<NBK * SPLIT, AGG_THREADS, 0, stream>>>(sorted, bucketPtr, th4, partial1, N);
    z_epilogue_kernel<<<nb, 256, 0, stream>>>(partial1, x, dinv, W1, b1, W2, z, N);
    agg2_partial_kernel<<<NBK * SPLIT, AGG_THREADS, 0, stream>>>(sorted, bucketPtr, z, p2, N);
    out_epilogue_kernel<<<nb, 256, 0, stream>>>(p2, z, dinv, b2, out, N);
}